// Round 6
// baseline (2059.032 us; speedup 1.0000x reference)
//
#include <hip/hip_runtime.h>
#include <hip/hip_bf16.h>

// Mlp_2_Layer_MMoE round 6: W-in-registers (64 VGPR/wave), X-in-LDS with XOR swizzle
// (conflict-free ds_read_b128), 1 barrier per 128-K chunk, reg prefetch.
// Pipeline: per-expert gemm1,gemm2 ; gates ; per-domain gemm4,gemm5,final.
// BN(training): raw sum/sumsq via shfl-reduced atomics; finalize in consumer prologue.

#define B_ROWS 131072
#define EPS_BN 1e-5f

typedef unsigned short bf_t;
typedef unsigned int u32;
typedef short bf16x8 __attribute__((ext_vector_type(8)));
typedef float f32x4  __attribute__((ext_vector_type(4)));

__device__ __forceinline__ float bf2f(bf_t u) { return __uint_as_float(((u32)u) << 16); }
__device__ __forceinline__ bf_t f2bf(float f) {
    u32 x = __float_as_uint(f);
    u32 r = x + 0x7FFFu + ((x >> 16) & 1u);   // round-to-nearest-even
    return (bf_t)(r >> 16);
}

// ---------------------------------------------------------------------------
// prep_w: WT[g][c][kk] = (kk<K && c<N) ? bf16(W[g][kk*N + c]) : 0
// ---------------------------------------------------------------------------
__global__ __launch_bounds__(256)
void prep_w(const float* __restrict__ W, bf_t* __restrict__ WT,
            int G, int K, int N, int CPAD, int KP)
{
    long total = (long)G * CPAD * KP;
    for (long idx = (long)blockIdx.x * 256 + threadIdx.x; idx < total;
         idx += (long)gridDim.x * 256) {
        int kk = (int)(idx % KP);
        long t = idx / KP;
        int c = (int)(t % CPAD);
        int g = (int)(t / CPAD);
        float v = 0.f;
        if (kk < K && c < N) v = W[((long)g * K + kk) * N + c];
        WT[idx] = f2bf(v);
    }
}

// ---------------------------------------------------------------------------
// prep_emb: embB[b][c] = bf16(emb[b][c]) zero-padded to 128, uint4 stores
// ---------------------------------------------------------------------------
__global__ __launch_bounds__(256)
void prep_emb(const float* __restrict__ emb, bf_t* __restrict__ embB)
{
    const long total = (long)B_ROWS * 16;          // 8-col units
    for (long idx = (long)blockIdx.x * 256 + threadIdx.x; idx < total;
         idx += (long)gridDim.x * 256) {
        long b = idx >> 4;
        int c0 = (int)(idx & 15) << 3;
        u32 o[4];
#pragma unroll
        for (int p = 0; p < 4; ++p) {
            int c = c0 + p * 2;
            float f0 = (c < 113)     ? emb[b * 113 + c]     : 0.f;
            float f1 = (c + 1 < 113) ? emb[b * 113 + c + 1] : 0.f;
            o[p] = (u32)f2bf(f0) | ((u32)f2bf(f1) << 16);
        }
        *(uint4*)&embB[b * 128 + c0] = make_uint4(o[0], o[1], o[2], o[3]);
    }
}

// ---------------------------------------------------------------------------
// gemm_big: Y[r][ycol0+c] = sum_k x(r,k) * WT[c][k] + bias[c]
//   XMODE 0: x = X[r*xrs + k]                  (bf16, pads zero)
//   XMODE 1: x = relu(bn(X[r*xrs + k])), ch=k
//   XMODE 2: x = sum_e gates[r*32+e]*relu(bn(X[r*480+e*120+k])), ch=e*113+k, k<Kreal
// Block: 512 thr = 8 waves (2 row-halves x 4 col-quarters), tile 128 rows x NOUT.
// W in REGISTERS (bw[CF][KT], 64 VGPR). X in LDS, 256B rows, XOR-swizzled
// (byte ^= (row&7)<<4 on write and read -> conflict-free b128). 1 barrier/chunk.
// SEL: store Y rows only where dom[row]==dsel (stats still over all rows).
// ---------------------------------------------------------------------------
template<int XMODE, int NOUT, int KPAD, bool SEL>
__global__ __launch_bounds__(512, 1)
void gemm_big(const bf_t* __restrict__ X, int xrs, int Kreal,
              const float* __restrict__ gates,
              const float* __restrict__ statS, const float* __restrict__ statQ,
              const float* __restrict__ gamma, const float* __restrict__ beta, int nchIn,
              const bf_t* __restrict__ WT,
              const float* __restrict__ bias, int Nvalid,
              bf_t* __restrict__ Y, int yrs, int ycol0,
              const int* __restrict__ dom, int dsel,
              float* __restrict__ oSum, float* __restrict__ oSq)
{
    constexpr int WCW = NOUT / 4;      // cols per wave (64 or 32)
    constexpr int CF  = WCW / 16;      // col frags per wave (4 or 2)
    constexpr int KT  = KPAD / 32;     // k-frags total (4 or 8)
    constexpr int NCH = KPAD / 128;    // 128-K chunks per tile (1 or 2)
    constexpr int TPB = 4;             // row tiles per block
    constexpr int NIT = TPB * NCH;

    __shared__ bf_t  XsL[2][128 * 128];     // 64 KB, 256B rows (swizzled)
    __shared__ float scS[512], shS[512];

    const int tid  = threadIdx.x;
    const int lane = tid & 63;
    const int w    = tid >> 6;
    const int wr   = w >> 2, wc = w & 3;
    const int g    = lane >> 4, lr = lane & 15;
    const int sr   = tid >> 2;              // staging row 0..127
    const int sq   = tid & 3;               // staging k-quarter
    const long tb0 = (long)blockIdx.x * TPB;

    // ---- W tile -> registers (once; k-bijection k = 8*g + e, both operands)
    bf16x8 bw[CF][KT];
#pragma unroll
    for (int ci = 0; ci < CF; ++ci) {
        const bf_t* wp = WT + (long)(wc * WCW + ci * 16 + lr) * KPAD + g * 8;
#pragma unroll
        for (int kt = 0; kt < KT; ++kt)
            bw[ci][kt] = *(const bf16x8*)(wp + kt * 32);
    }
    // ---- input-BN scale/shift
    if (XMODE != 0) {
        for (int c = tid; c < nchIn; c += 512) {
            float m = statS[c] * (1.f / B_ROWS);
            float v = statQ[c] * (1.f / B_ROWS) - m * m;
            float s = gamma[c] * rsqrtf(v + EPS_BN);
            scS[c] = s;
            shS[c] = beta[c] - m * s;
        }
    }
    float bj[CF];
#pragma unroll
    for (int ci = 0; ci < CF; ++ci) {
        int col = wc * WCW + ci * 16 + lr;
        bj[ci] = (col < Nvalid) ? bias[col] : 0.f;
    }
    __syncthreads();   // scS ready (staging reads it)

    f32x4 acc[4][CF];
#pragma unroll
    for (int ri = 0; ri < 4; ++ri)
#pragma unroll
        for (int ci = 0; ci < CF; ++ci) acc[ri][ci] = (f32x4){0.f, 0.f, 0.f, 0.f};
    float csum[CF], csq[CF];
#pragma unroll
    for (int ci = 0; ci < CF; ++ci) { csum[ci] = 0.f; csq[ci] = 0.f; }

    // swizzled LDS write ptr for (sr, sq, j)
    auto ldsw = [&](int buf, int j) -> char* {
        int byte = (sr << 8) + (sq << 6) + (j << 4);
        byte ^= (sr & 7) << 4;
        return (char*)XsL[buf] + byte;
    };
    auto issue4 = [&](int it, uint4* r) {       // XMODE 0/1 global loads
        int t = it / NCH, ck = (it % NCH) << 7;
        const bf_t* p = X + ((tb0 + t) * 128 + sr) * (long)xrs + ck + (sq << 5);
#pragma unroll
        for (int j = 0; j < 4; ++j) r[j] = *(const uint4*)(p + j * 8);
    };
    auto twrite = [&](int it, const uint4* r) { // transform + swizzled LDS write
        int buf = it & 1;
        if (XMODE == 0) {
#pragma unroll
            for (int j = 0; j < 4; ++j) *(uint4*)ldsw(buf, j) = r[j];
        } else {
            int kb = ((it % NCH) << 7) + (sq << 5);
#pragma unroll
            for (int j = 0; j < 4; ++j) {
                u32 q[4] = {r[j].x, r[j].y, r[j].z, r[j].w};
                u32 o[4];
#pragma unroll
                for (int p2 = 0; p2 < 4; ++p2) {
                    int k0 = kb + j * 8 + p2 * 2;
                    float f0 = fmaxf(bf2f((bf_t)(q[p2] & 0xffffu)) * scS[k0] + shS[k0], 0.f);
                    float f1 = fmaxf(bf2f((bf_t)(q[p2] >> 16)) * scS[k0 + 1] + shS[k0 + 1], 0.f);
                    o[p2] = (u32)f2bf(f0) | ((u32)f2bf(f1) << 16);
                }
                *(uint4*)ldsw(buf, j) = make_uint4(o[0], o[1], o[2], o[3]);
            }
        }
    };
    auto stage2 = [&](int it) {                 // XMODE 2: gated mix, JIT
        long row = (tb0 + it) * 128 + sr;       // NCH==1
        float4 g4v = *(const float4*)&gates[row * 32];
        float ge[4] = {g4v.x, g4v.y, g4v.z, g4v.w};
        int buf = it & 1;
#pragma unroll
        for (int j = 0; j < 4; ++j) {
            int kb = (sq << 5) + j * 8;
            uint4 re[4];
#pragma unroll
            for (int e = 0; e < 4; ++e)
                re[e] = *(const uint4*)&X[row * 480 + e * 120 + kb];
            float vv[8];
#pragma unroll
            for (int p2 = 0; p2 < 8; ++p2) vv[p2] = 0.f;
#pragma unroll
            for (int e = 0; e < 4; ++e) {
                u32 q[4] = {re[e].x, re[e].y, re[e].z, re[e].w};
#pragma unroll
                for (int p2 = 0; p2 < 8; ++p2) {
                    int k = kb + p2;
                    if (k < Kreal) {
                        float f = bf2f((bf_t)((q[p2 >> 1] >> ((p2 & 1) * 16)) & 0xffffu));
                        int ch = e * 113 + k;
                        f = fmaxf(f * scS[ch] + shS[ch], 0.f);
                        vv[p2] = fmaf(ge[e], f, vv[p2]);
                    }
                }
            }
            u32 o[4];
#pragma unroll
            for (int p2 = 0; p2 < 4; ++p2)
                o[p2] = (u32)f2bf(vv[p2 * 2]) | ((u32)f2bf(vv[p2 * 2 + 1]) << 16);
            *(uint4*)ldsw(buf, j) = make_uint4(o[0], o[1], o[2], o[3]);
        }
    };
    auto do_mfma = [&](int it) {
        const char* xb = (const char*)XsL[it & 1];
        const int kg0 = (it % NCH) * 4;
#pragma unroll
        for (int kt = 0; kt < 4; ++kt) {
            bf16x8 af[4];
#pragma unroll
            for (int ri = 0; ri < 4; ++ri) {
                int row = wr * 64 + ri * 16 + lr;
                int byte = (row << 8) + (kt << 6) + (g << 4);
                byte ^= (lr & 7) << 4;          // row&7 == lr&7 (row base mult of 16)
                af[ri] = *(const bf16x8*)(xb + byte);
            }
#pragma unroll
            for (int ci = 0; ci < CF; ++ci)
#pragma unroll
                for (int ri = 0; ri < 4; ++ri)
                    acc[ri][ci] = __builtin_amdgcn_mfma_f32_16x16x32_bf16(
                        af[ri], bw[ci][kg0 + kt], acc[ri][ci], 0, 0, 0);
        }
    };
    auto epi = [&](int t) {
        const long row0 = (tb0 + t) * 128;
#pragma unroll
        for (int ci = 0; ci < CF; ++ci) {
            int col = wc * WCW + ci * 16 + lr;
            bool cv = col < Nvalid;
#pragma unroll
            for (int ri = 0; ri < 4; ++ri) {
#pragma unroll
                for (int reg = 0; reg < 4; ++reg) {
                    long row = row0 + wr * 64 + ri * 16 + g * 4 + reg;
                    float y = acc[ri][ci][reg] + bj[ci];
                    csum[ci] += y;
                    csq[ci]  += y * y;
                    bool st = cv;
                    if (SEL) st = st && (dom[row] == dsel);
                    if (st) Y[row * (long)yrs + ycol0 + col] = f2bf(y);
                    acc[ri][ci][reg] = 0.f;
                }
            }
        }
    };

    // ---- main loop: 1 barrier per chunk, dbuf rotation, reg prefetch
    if (XMODE != 2) {
        uint4 rA[4], rB[4];
        issue4(0, rA);
#pragma unroll 1
        for (int ip = 0; ip < NIT; ip += 2) {
            if (ip + 1 < NIT) issue4(ip + 1, rB);
            twrite(ip, rA);
            __syncthreads();
            do_mfma(ip);
            if ((ip % NCH) == NCH - 1) epi(ip / NCH);
            if (ip + 2 < NIT) issue4(ip + 2, rA);
            twrite(ip + 1, rB);
            __syncthreads();
            do_mfma(ip + 1);
            if (((ip + 1) % NCH) == NCH - 1) epi((ip + 1) / NCH);
        }
    } else {
#pragma unroll 1
        for (int it = 0; it < NIT; ++it) {
            stage2(it);
            __syncthreads();
            do_mfma(it);
            epi(it);
        }
    }

    // ---- stats flush: shfl over lane groups, one atomic per col per wave
#pragma unroll
    for (int ci = 0; ci < CF; ++ci) {
        float s = csum[ci], q = csq[ci];
        s += __shfl_xor(s, 16); s += __shfl_xor(s, 32);
        q += __shfl_xor(q, 16); q += __shfl_xor(q, 32);
        if (lane < 16) {
            int col = wc * WCW + ci * 16 + lane;
            if (col < Nvalid) {
                atomicAdd(&oSum[col], s);
                atomicAdd(&oSq[col], q);
            }
        }
    }
}

// ---------------------------------------------------------------------------
// gates: gates[b][d*4+e] = softmax_e(emb[b] . Wg[d][:,e] + bg[d][e])
// ---------------------------------------------------------------------------
__global__ __launch_bounds__(256)
void gates_kernel(const float* __restrict__ emb, const float* __restrict__ Wg,
                  const float* __restrict__ bg, float* __restrict__ gates)
{
    __shared__ float embS[64][116];
    __shared__ float WgS[8 * 113 * 4];
    __shared__ float bgS[32];
    const int tid = threadIdx.x;
    const int r0 = blockIdx.x << 6;

    for (int idx = tid; idx < 64 * 113; idx += 256) {
        int rr = idx / 113, kk = idx - rr * 113;
        embS[rr][kk] = emb[(long)(r0 + rr) * 113 + kk];
    }
    for (int idx = tid; idx < 8 * 113 * 4; idx += 256) WgS[idx] = Wg[idx];
    if (tid < 32) bgS[tid] = bg[tid];
    __syncthreads();

    const int q = tid & 3;
    const int r = tid >> 2;
#pragma unroll
    for (int p = 0; p < 2; ++p) {
        int d = q + p * 4;
        float lg[4] = {bgS[d * 4 + 0], bgS[d * 4 + 1], bgS[d * 4 + 2], bgS[d * 4 + 3]};
        for (int k = 0; k < 113; ++k) {
            float x = embS[r][k];
            const float* wp = &WgS[(d * 113 + k) * 4];
#pragma unroll
            for (int e = 0; e < 4; ++e) lg[e] = fmaf(x, wp[e], lg[e]);
        }
        float m = fmaxf(fmaxf(lg[0], lg[1]), fmaxf(lg[2], lg[3]));
        float ex[4], s = 0.f;
#pragma unroll
        for (int e = 0; e < 4; ++e) { ex[e] = expf(lg[e] - m); s += ex[e]; }
        float inv = 1.f / s;
        *(float4*)&gates[(long)(r0 + r) * 32 + d * 4] =
            make_float4(ex[0] * inv, ex[1] * inv, ex[2] * inv, ex[3] * inv);
    }
}

// ---------------------------------------------------------------------------
// final (per domain d): rows with dom[b]==d:
//   out[b] = sigmoid( relu(bn4(Y4d[b][:])) . w3 + b3 )
// ---------------------------------------------------------------------------
__global__ __launch_bounds__(256)
void final_kernel(const bf_t* __restrict__ Y4d, const int* __restrict__ dom,
                  const float* __restrict__ s4sum, const float* __restrict__ s4sq,
                  const float* __restrict__ g4, const float* __restrict__ b4,
                  const float* __restrict__ w3, const float* __restrict__ b3,
                  int d, float* __restrict__ out)
{
    __shared__ float sc[128], sh[128], wS[128];
    const int tid = threadIdx.x;
    if (tid < 128) {
        float m = s4sum[tid] * (1.f / B_ROWS);
        float v = s4sq[tid] * (1.f / B_ROWS) - m * m;
        float s = g4[tid] * rsqrtf(v + EPS_BN);
        sc[tid] = s;
        sh[tid] = b4[tid] - m * s;
        wS[tid] = w3[tid];
    }
    __syncthreads();
    const float bb = b3[0];
    for (long b = (long)blockIdx.x * 256 + tid; b < B_ROWS; b += (long)gridDim.x * 256) {
        if ((dom[b] & 7) == d) {
            const bf_t* yp = Y4d + b * 128;
            float acc = bb;
            for (int c = 0; c < 128; c += 8) {
                uint4 raw = *(const uint4*)(yp + c);
                u32 w4[4] = {raw.x, raw.y, raw.z, raw.w};
#pragma unroll
                for (int j = 0; j < 8; ++j) {
                    float f = bf2f((bf_t)((w4[j >> 1] >> ((j & 1) * 16)) & 0xffffu));
                    float h = fmaxf(f * sc[c + j] + sh[c + j], 0.f);
                    acc = fmaf(h, wS[c + j], acc);
                }
            }
            out[b] = 1.f / (1.f + expf(-acc));
        }
    }
}

// ---------------------------------------------------------------------------
extern "C" void kernel_launch(void* const* d_in, const int* in_sizes, int n_in,
                              void* d_out, int out_size, void* d_ws, size_t ws_size,
                              hipStream_t stream)
{
    const float* emb = (const float*)d_in[0];
    const int*   dom = (const int*)d_in[1];
    const float* We1 = (const float*)d_in[2];
    const float* be1 = (const float*)d_in[3];
    const float* eg1 = (const float*)d_in[4];
    const float* eb1 = (const float*)d_in[5];
    const float* We2 = (const float*)d_in[6];
    const float* be2 = (const float*)d_in[7];
    const float* eg2 = (const float*)d_in[8];
    const float* eb2 = (const float*)d_in[9];
    const float* Wg  = (const float*)d_in[10];
    const float* bg  = (const float*)d_in[11];
    const float* Wt1 = (const float*)d_in[12];
    const float* bt1 = (const float*)d_in[13];
    const float* tg1 = (const float*)d_in[14];
    const float* tb1 = (const float*)d_in[15];
    const float* Wt2 = (const float*)d_in[16];
    const float* bt2 = (const float*)d_in[17];
    const float* tg2 = (const float*)d_in[18];
    const float* tb2 = (const float*)d_in[19];
    const float* Wt3 = (const float*)d_in[20];
    const float* bt3 = (const float*)d_in[21];
    float* out = (float*)d_out;

    char* ws = (char*)d_ws;
    // workspace layout (peak ~244.9 MB):
    bf_t*  Y2    = (bf_t*)(ws);                    // [B][480] bf16, 125.8 MB
    float* gates = (float*)(ws + 125829120LL);     // [B][32] f32, 16.8 MB
    bf_t*  Yx    = (bf_t*)(ws + 142606336LL);      // Y1e / Y3d slot: [B][256] bf16, 67.1 MB
    bf_t*  Y4    = (bf_t*)(ws + 209715200LL);      // [B][128] bf16 (embB first), 33.55 MB
    float* S     = (float*)(ws + 243269632LL);     // raw stats, 9096 f32
    bf_t*  WTa   = (bf_t*)(ws + 243306496LL);      // transposed bf16 weights, 1.5 MB

    bf_t* embB = Y4;                 // dead before gemm5 writes Y4
    bf_t* We1T = WTa;                // [4][256][128]
    bf_t* We2T = We1T + 131072;      // [4][128][256]
    bf_t* Wt1T = We2T + 131072;      // [8][256][128]
    bf_t* Wt2T = Wt1T + 262144;      // [8][128][256]

    float* S1s = S;           float* S1q = S1s + 1024;   // [4][256]
    float* S2s = S1q + 1024;  float* S2q = S2s + 452;    // [4][113]
    float* S3s = S2q + 452;   float* S3q = S3s + 2048;   // [8][256]
    float* S4s = S3q + 2048;  float* S4q = S4s + 1024;   // [8][128]

    hipMemsetAsync(S, 0, 9096 * sizeof(float), stream);

    // ---- prep ----
    prep_w<<<512, 256, 0, stream>>>(We1, We1T, 4, 113, 256, 256, 128);
    prep_w<<<512, 256, 0, stream>>>(We2, We2T, 4, 256, 113, 128, 256);
    prep_w<<<1024, 256, 0, stream>>>(Wt1, Wt1T, 8, 113, 256, 256, 128);
    prep_w<<<1024, 256, 0, stream>>>(Wt2, Wt2T, 8, 256, 128, 128, 256);
    prep_emb<<<2048, 256, 0, stream>>>(emb, embB);

    // ---- gates ----
    gates_kernel<<<2048, 256, 0, stream>>>(emb, Wg, bg, gates);

    // ---- expert phase ----
    for (int e = 0; e < 4; ++e) {
        // gemm1: embB [B,128](113) -> Y1e [B,256] + S1[e]
        gemm_big<0, 256, 128, false><<<256, 512, 0, stream>>>(
            embB, 128, 128,
            nullptr, nullptr, nullptr, nullptr, nullptr, 0,
            We1T + (long)e * 32768,
            be1 + e * 256, 256,
            Yx, 256, 0, nullptr, 0, S1s + e * 256, S1q + e * 256);
        // gemm2: relu(bn1(Y1e)) [B,256] -> Y2[:, e*120..+113] + S2[e]
        gemm_big<1, 128, 256, false><<<256, 512, 0, stream>>>(
            Yx, 256, 256,
            nullptr, S1s + e * 256, S1q + e * 256, eg1 + e * 256, eb1 + e * 256, 256,
            We2T + (long)e * 32768,
            be2 + e * 113, 113,
            Y2, 480, e * 120, nullptr, 0, S2s + e * 113, S2q + e * 113);
    }

    // ---- tower phase ----
    for (int d = 0; d < 8; ++d) {
        // gemm4: gated mix of bn2+relu(Y2) [B,113] -> Y3d [B,256] + S3[d]
        gemm_big<2, 256, 128, false><<<256, 512, 0, stream>>>(
            Y2, 480, 113,
            gates + d * 4, S2s, S2q, eg2, eb2, 452,
            Wt1T + (long)d * 32768,
            bt1 + d * 256, 256,
            Yx, 256, 0, nullptr, 0, S3s + d * 256, S3q + d * 256);
        // gemm5: relu(bn3(Y3d)) [B,256] -> Y4d [B,128] (rows with dom==d only) + S4[d]
        gemm_big<1, 128, 256, true><<<256, 512, 0, stream>>>(
            Yx, 256, 256,
            nullptr, S3s + d * 256, S3q + d * 256, tg1 + d * 256, tb1 + d * 256, 256,
            Wt2T + (long)d * 32768,
            bt2 + d * 128, 128,
            Y4, 128, 0, dom, d, S4s + d * 128, S4q + d * 128);
        // final: select rows with dom==d, bn4+relu, dot Wt3, sigmoid
        final_kernel<<<1024, 256, 0, stream>>>(
            Y4, dom, S4s + d * 128, S4q + d * 128,
            tg2 + d * 128, tb2 + d * 128, Wt3 + d * 128, bt3 + d, d, out);
    }

    (void)in_sizes; (void)n_in; (void)out_size; (void)ws_size;
}